// Round 1
// 525.175 us; speedup vs baseline: 1.3456x; 1.3456x over previous
//
#include <hip/hip_runtime.h>
#include <cstdint>
#include <cstddef>

#define N_ROWS 262144
#define D 256
#define K_CODES 640
#define BM 64
#define BK 32
#define TAU 0.05f         // flag threshold: ~7x worst-case split-bf16 score error (~7e-3)

typedef __attribute__((ext_vector_type(8))) short bf16x8;
typedef __attribute__((ext_vector_type(4))) float f32x4;

__constant__ int d_STARTS[6] = {0, 129, 257, 385, 513, 577};
__constant__ int d_ENDS[6]   = {128, 256, 384, 512, 576, 640};

__device__ __forceinline__ int partition_id(int a) {
    int p = 3;
    if (a == 5) p = 0;
    else if (a == 6) p = 1;
    else if (a == 7) p = 2;
    else if (a == 119) p = 4;
    else if (a == 120) p = 5;
    return p;
}

__device__ __forceinline__ unsigned short f32_to_bf16_rne(float x) {
    unsigned int u = __float_as_uint(x);
    u += 0x7FFFu + ((u >> 16) & 1u);
    return (unsigned short)(u >> 16);
}

// ---- ws layout (bytes) ----
// 0      : double loss accumulator
// 8      : double wnorm2[640]
// 5128   : int counts[6]
// 5152   : int bases[6]
// 5176   : int cursors[6]
// 5200   : int flagcnt
// 5208   : float wnormf[640]
// 8192   : int rowlist[N]
// 8192+4N: int flagrows[N]
// 8192+8N: ushort wfrag[6*8*1024*8]   (786432 B, MFMA-fragment order, hi/lo bf16)

__global__ void k_zero(int* ws_i) {
    int t = threadIdx.x;
    for (int i = t; i < 2048; i += 256) ws_i[i] = 0;
}

__global__ void k_wnorm(const float* __restrict__ w, double* __restrict__ wnorm2,
                        float* __restrict__ wnormf) {
    int k = blockIdx.x;
    int l = threadIdx.x;  // 64 threads
    const float* row = w + (size_t)k * D;
    double s = 0.0;
    for (int j = l; j < D; j += 64) {
        double v = (double)row[j];
        s += v * v;
    }
    #pragma unroll
    for (int m = 32; m > 0; m >>= 1) s += __shfl_xor(s, m, 64);
    if (l == 0) { wnorm2[k] = s; wnormf[k] = (float)s; }
}

// Precompute w in split-bf16 MFMA-fragment order:
// wfrag[(p*8+kt)*1024 + h*512 + ct*64 + lane] = 8 bf16 (16B)
// lane slot holds code row cs+16*ct+(lane&15), k-cols kt*32+8*(lane>>4)..+7
__global__ void k_wfrag(const float* __restrict__ w, unsigned short* __restrict__ wfrag) {
    int blk = blockIdx.x;            // 48 = p*8 + kt
    int p = blk >> 3, kt = blk & 7;
    int cs = d_STARTS[p], ce = d_ENDS[p];
    int t = threadIdx.x;             // 256
    #pragma unroll
    for (int i = 0; i < 4; i++) {
        int s = i * 256 + t;         // slot 0..1023
        int h = s >> 9;
        int ct = (s >> 6) & 7;
        int lane = s & 63;
        int k = cs + 16 * ct + (lane & 15);
        int c0 = kt * 32 + 8 * (lane >> 4);
        unsigned v0 = 0, v1 = 0, v2 = 0, v3 = 0;
        if (k < ce) {
            const float* row = w + (size_t)k * D + c0;
            unsigned vv[4];
            #pragma unroll
            for (int j = 0; j < 4; j++) {
                float x0 = row[2 * j], x1 = row[2 * j + 1];
                unsigned short a0 = f32_to_bf16_rne(x0), a1 = f32_to_bf16_rne(x1);
                if (h) {
                    float y0 = x0 - __uint_as_float((unsigned)a0 << 16);
                    float y1 = x1 - __uint_as_float((unsigned)a1 << 16);
                    a0 = f32_to_bf16_rne(y0);
                    a1 = f32_to_bf16_rne(y1);
                }
                vv[j] = (unsigned)a0 | ((unsigned)a1 << 16);
            }
            v0 = vv[0]; v1 = vv[1]; v2 = vv[2]; v3 = vv[3];
        }
        *(uint4*)(wfrag + ((size_t)blk * 1024 + s) * 8) = make_uint4(v0, v1, v2, v3);
    }
}

__global__ void k_count(const int* __restrict__ x, int* __restrict__ counts) {
    __shared__ int lc[6];
    int t = threadIdx.x;  // 1024
    if (t < 6) lc[t] = 0;
    __syncthreads();
    int r = blockIdx.x * 1024 + t;
    atomicAdd(&lc[partition_id(x[2 * r])], 1);
    __syncthreads();
    if (t < 6) atomicAdd(&counts[t], lc[t]);
}

__global__ void k_scan(const int* __restrict__ counts, int* __restrict__ bases,
                       int* __restrict__ cursors) {
    if (threadIdx.x == 0) {
        int b = 0;
        for (int p = 0; p < 6; p++) {
            bases[p] = b;
            cursors[p] = b;
            b += counts[p];
        }
    }
}

// Block-aggregated scatter: 6 global atomics per 1024-thread block.
__global__ void k_scatter(const int* __restrict__ x, int* __restrict__ cursors,
                          int* __restrict__ rowlist) {
    __shared__ int wcnt[16][6];
    __shared__ int bbase[6];
    int t = threadIdx.x;
    int wid = t >> 6, lane = t & 63;
    int r = blockIdx.x * 1024 + t;
    int p = partition_id(x[2 * r]);
    unsigned long long mym = 0;
    #pragma unroll
    for (int q = 0; q < 6; q++) {
        unsigned long long m = __ballot(p == q);
        if (p == q) mym = m;
        if (lane == 0) wcnt[wid][q] = __popcll(m);
    }
    __syncthreads();
    if (t < 6) {
        int s = 0;
        for (int w2 = 0; w2 < 16; w2++) { int c = wcnt[w2][t]; wcnt[w2][t] = s; s += c; }
        bbase[t] = atomicAdd(&cursors[t], s);
    }
    __syncthreads();
    int pos = bbase[p] + wcnt[wid][p] + __popcll(mym & ((1ull << lane) - 1ull));
    rowlist[pos] = r;
}

// Pass A: split-bf16 MFMA GEMM. Block = 64 rows x 128 codes, 4 waves, acc[8] per wave.
// A staged in fragment order (conflict-free b128); B DMA'd from precomputed wfrag via
// global_load_lds (no VALU, linear LDS dest == fragment order).
__launch_bounds__(256, 5)
__global__ void k_passA(const float* __restrict__ e, const float* __restrict__ w,
                        const int* __restrict__ counts, const int* __restrict__ bases,
                        const int* __restrict__ rowlist, const unsigned short* __restrict__ wfrag,
                        const float* __restrict__ wnormf,
                        float* __restrict__ out, double* __restrict__ loss,
                        int* __restrict__ flagcnt, int* __restrict__ flagrows) {
    int b = blockIdx.x;
    int p = -1, seg = 0;
    {
        int acc0 = 0;
        for (int q = 0; q < 6; q++) {
            int nb = (counts[q] + BM - 1) / BM;
            if (b < acc0 + nb) { p = q; seg = b - acc0; break; }
            acc0 += nb;
        }
    }
    if (p < 0) return;

    int cstart = d_STARTS[p], cend = d_ENDS[p];
    int cnt = counts[p];
    int base = bases[p] + seg * BM;
    int nrows = min(BM, cnt - seg * BM);

    __shared__ int rl[BM];
    __shared__ float wnf[128];
    __shared__ int bestk[BM];
    __shared__ double lred[4];
    __shared__ __align__(16) unsigned short Ah[4][64][8];   // [wave group][lane slot][8 bf16]
    __shared__ __align__(16) unsigned short Al[4][64][8];
    __shared__ __align__(16) unsigned short Bf[2][8][64][8]; // [hi/lo][ct][lane][8 bf16]

    int tid = threadIdx.x;
    int lane = tid & 63;
    int wid = tid >> 6;
    int m16 = lane & 15;

    if (tid < BM) rl[tid] = (tid < nrows) ? rowlist[base + tid] : -1;
    if (tid < 128) {
        int k = cstart + tid;
        wnf[tid] = (k < cend) ? wnormf[k] : __int_as_float(0x7f800000);
    }
    __syncthreads();

    f32x4 acc[8];
    #pragma unroll
    for (int ct = 0; ct < 8; ct++) acc[ct] = (f32x4){0.f, 0.f, 0.f, 0.f};

    double lsum = 0.0;

    int srow = tid >> 2;          // staged row 0..63
    int q4 = tid & 3;             // which 8-col chunk of the 32-wide tile
    int gr = rl[srow];
    const float* ebase = e + (size_t)(gr < 0 ? 0 : gr) * D + 8 * q4;
    unsigned short* aw_h = &Ah[srow >> 4][(srow & 15) + 16 * q4][0];
    unsigned short* aw_l = &Al[srow >> 4][(srow & 15) + 16 * q4][0];
    const unsigned short* wtile = wfrag + (size_t)p * 8 * 8192;  // 8192 ushorts per k-tile
    unsigned short* bbuf = &Bf[0][0][0][0];

    #pragma unroll 1
    for (int t0 = 0; t0 < D; t0 += BK) {
        // issue B DMA (overlaps A conversion below; prior trailing barrier protects LDS)
        {
            const unsigned short* wt = wtile + (size_t)(t0 >> 5) * 8192;
            #pragma unroll
            for (int i = 0; i < 4; i++) {
                int ws_ = i * 256 + wid * 64;  // wave-uniform slot base
                __builtin_amdgcn_global_load_lds(
                    (const __attribute__((address_space(1))) unsigned int*)(wt + (size_t)(ws_ + lane) * 8),
                    (__attribute__((address_space(3))) unsigned int*)(bbuf + (size_t)ws_ * 8),
                    16, 0, 0);
            }
        }
        // stage A: 8 consecutive floats -> split bf16, fragment-order LDS write
        {
            float4 ev0 = make_float4(0.f, 0.f, 0.f, 0.f);
            float4 ev1 = make_float4(0.f, 0.f, 0.f, 0.f);
            if (gr >= 0) {
                ev0 = *(const float4*)(ebase + t0);
                ev1 = *(const float4*)(ebase + t0 + 4);
            }
            float n0 = ev0.x * ev0.x + ev0.y * ev0.y + ev0.z * ev0.z + ev0.w * ev0.w;
            float n1 = ev1.x * ev1.x + ev1.y * ev1.y + ev1.z * ev1.z + ev1.w * ev1.w;
            lsum += (double)(n0 + n1);
            unsigned short h0 = f32_to_bf16_rne(ev0.x), h1 = f32_to_bf16_rne(ev0.y);
            unsigned short h2 = f32_to_bf16_rne(ev0.z), h3 = f32_to_bf16_rne(ev0.w);
            unsigned short h4 = f32_to_bf16_rne(ev1.x), h5 = f32_to_bf16_rne(ev1.y);
            unsigned short h6 = f32_to_bf16_rne(ev1.z), h7 = f32_to_bf16_rne(ev1.w);
            float r0 = ev0.x - __uint_as_float((unsigned)h0 << 16);
            float r1 = ev0.y - __uint_as_float((unsigned)h1 << 16);
            float r2 = ev0.z - __uint_as_float((unsigned)h2 << 16);
            float r3 = ev0.w - __uint_as_float((unsigned)h3 << 16);
            float r4 = ev1.x - __uint_as_float((unsigned)h4 << 16);
            float r5 = ev1.y - __uint_as_float((unsigned)h5 << 16);
            float r6 = ev1.z - __uint_as_float((unsigned)h6 << 16);
            float r7 = ev1.w - __uint_as_float((unsigned)h7 << 16);
            uint4 hp = make_uint4((unsigned)h0 | ((unsigned)h1 << 16),
                                  (unsigned)h2 | ((unsigned)h3 << 16),
                                  (unsigned)h4 | ((unsigned)h5 << 16),
                                  (unsigned)h6 | ((unsigned)h7 << 16));
            uint4 lp = make_uint4((unsigned)f32_to_bf16_rne(r0) | ((unsigned)f32_to_bf16_rne(r1) << 16),
                                  (unsigned)f32_to_bf16_rne(r2) | ((unsigned)f32_to_bf16_rne(r3) << 16),
                                  (unsigned)f32_to_bf16_rne(r4) | ((unsigned)f32_to_bf16_rne(r5) << 16),
                                  (unsigned)f32_to_bf16_rne(r6) | ((unsigned)f32_to_bf16_rne(r7) << 16));
            *(uint4*)aw_h = hp;
            *(uint4*)aw_l = lp;
        }
        __syncthreads();   // drains vmcnt (B DMA) + lgkm (A writes)

        bf16x8 a_h = *(const bf16x8*)&Ah[wid][lane][0];
        bf16x8 a_l = *(const bf16x8*)&Al[wid][lane][0];
        #pragma unroll
        for (int ct = 0; ct < 8; ct++) {
            bf16x8 b_h = *(const bf16x8*)&Bf[0][ct][lane][0];
            bf16x8 b_l = *(const bf16x8*)&Bf[1][ct][lane][0];
            acc[ct] = __builtin_amdgcn_mfma_f32_16x16x32_bf16(a_h, b_h, acc[ct], 0, 0, 0);
            acc[ct] = __builtin_amdgcn_mfma_f32_16x16x32_bf16(a_l, b_h, acc[ct], 0, 0, 0);
            acc[ct] = __builtin_amdgcn_mfma_f32_16x16x32_bf16(a_h, b_l, acc[ct], 0, 0, 0);
        }
        __syncthreads();   // protect LDS before next tile's stage
    }

    // epilogue: per-lane wnorm for its 8 cols
    float wl[8];
    #pragma unroll
    for (int ct = 0; ct < 8; ct++) wl[ct] = wnf[16 * ct + m16];

    const float INFF = __int_as_float(0x7f800000);
    #pragma unroll
    for (int reg = 0; reg < 4; reg++) {
        int slot = 16 * wid + (lane >> 4) * 4 + reg;
        float b1 = INFF, b2 = INFF;
        int c1 = 1 << 30, c2 = 1 << 30;
        #pragma unroll
        for (int ct = 0; ct < 8; ct++) {
            float s = wl[ct] - 2.0f * acc[ct][reg];
            int k = cstart + 16 * ct + m16;
            if (s < b1) { b2 = b1; c2 = c1; b1 = s; c1 = k; }
            else if (s < b2) { b2 = s; c2 = k; }
        }
        #pragma unroll
        for (int m = 1; m < 16; m <<= 1) {
            float ob1 = __shfl_xor(b1, m, 64), ob2 = __shfl_xor(b2, m, 64);
            int oc1 = __shfl_xor(c1, m, 64), oc2 = __shfl_xor(c2, m, 64);
            bool oWins = (ob1 < b1) || (ob1 == b1 && oc1 < c1);
            if (oWins) {
                float nb2; int nc2;
                if (b1 < ob2 || (b1 == ob2 && c1 < oc2)) { nb2 = b1; nc2 = c1; }
                else { nb2 = ob2; nc2 = oc2; }
                b1 = ob1; c1 = oc1; b2 = nb2; c2 = nc2;
            } else {
                if (ob1 < b2 || (ob1 == b2 && oc1 < c2)) { b2 = ob1; c2 = oc1; }
            }
        }
        if (m16 == 0) {
            if (slot < nrows) {
                if (b2 - b1 < TAU) {
                    int pos = atomicAdd(flagcnt, 1);
                    flagrows[pos] = rl[slot];
                    bestk[slot] = -1;
                } else {
                    bestk[slot] = c1;
                    lsum += (double)b1;
                }
            } else {
                bestk[slot] = -1;
            }
        }
    }
    __syncthreads();

    // write out rows, wave-per-row float4, skipping flagged
    for (int rsl = wid; rsl < nrows; rsl += 4) {
        int k = bestk[rsl];
        if (k >= 0) {
            int g = rl[rsl];
            *(float4*)(out + (size_t)g * D + 4 * lane) =
                *(const float4*)(w + (size_t)k * D + 4 * lane);
        }
    }

    #pragma unroll
    for (int m = 32; m > 0; m >>= 1) lsum += __shfl_xor(lsum, m, 64);
    if (lane == 0) lred[wid] = lsum;
    __syncthreads();
    if (tid == 0) atomicAdd(loss, lred[0] + lred[1] + lred[2] + lred[3]);
}

// Pass B: exact fp64 re-evaluation of flagged rows. 512 blocks, grid-stride.
__global__ void k_passB(const float* __restrict__ e, const float* __restrict__ w,
                        const int* __restrict__ x, const double* __restrict__ wnorm2,
                        const int* __restrict__ flagcnt, const int* __restrict__ flagrows,
                        float* __restrict__ out, double* __restrict__ loss) {
    __shared__ float eL[D];
    __shared__ double sc[128];
    __shared__ int sk[128];
    int t = threadIdx.x;
    int nf = *flagcnt;
    for (int f = blockIdx.x; f < nf; f += gridDim.x) {
        int gr = flagrows[f];
        eL[t] = e[(size_t)gr * D + t];
        __syncthreads();
        int p = partition_id(x[2 * gr]);
        int cs = d_STARTS[p], ce = d_ENDS[p];
        if (t < 128) {
            int k = cs + t;
            if (k < ce) {
                const float* wr = w + (size_t)k * D;
                double d0 = 0.0, d1 = 0.0, d2 = 0.0, d3 = 0.0;
                #pragma unroll 4
                for (int d = 0; d < D; d += 4) {
                    d0 += (double)eL[d + 0] * (double)wr[d + 0];
                    d1 += (double)eL[d + 1] * (double)wr[d + 1];
                    d2 += (double)eL[d + 2] * (double)wr[d + 2];
                    d3 += (double)eL[d + 3] * (double)wr[d + 3];
                }
                sc[t] = wnorm2[k] - 2.0 * ((d0 + d1) + (d2 + d3));
                sk[t] = k;
            } else {
                sc[t] = 1e300;
                sk[t] = 1 << 30;
            }
        }
        __syncthreads();
        for (int s = 64; s > 0; s >>= 1) {
            if (t < s) {
                double o = sc[t + s]; int ok = sk[t + s];
                if (o < sc[t] || (o == sc[t] && ok < sk[t])) { sc[t] = o; sk[t] = ok; }
            }
            __syncthreads();
        }
        int bk = sk[0];
        out[(size_t)gr * D + t] = w[(size_t)bk * D + t];
        if (t == 0) atomicAdd(loss, sc[0]);
        __syncthreads();
    }
}

__global__ void k_final(const double* __restrict__ loss, float* __restrict__ out) {
    if (threadIdx.x == 0) {
        double mean = *loss / ((double)N_ROWS * (double)D);
        size_t nd = (size_t)N_ROWS * D;
        out[nd + 0] = (float)mean;
        out[nd + 1] = (float)mean;
        out[nd + 2] = (float)(1.25 * mean);
    }
}

extern "C" void kernel_launch(void* const* d_in, const int* in_sizes, int n_in,
                              void* d_out, int out_size, void* d_ws, size_t ws_size,
                              hipStream_t stream) {
    const int* x = (const int*)d_in[0];
    const float* e = (const float*)d_in[1];
    const float* w = (const float*)d_in[2];
    float* out = (float*)d_out;
    char* ws = (char*)d_ws;

    double* loss    = (double*)(ws + 0);
    double* wnorm2  = (double*)(ws + 8);
    int* counts     = (int*)(ws + 5128);
    int* bases      = (int*)(ws + 5152);
    int* cursors    = (int*)(ws + 5176);
    int* flagcnt    = (int*)(ws + 5200);
    float* wnormf   = (float*)(ws + 5208);
    int* rowlist    = (int*)(ws + 8192);
    int* flagrows   = (int*)(ws + 8192 + 4 * (size_t)N_ROWS);
    unsigned short* wfrag = (unsigned short*)(ws + 8192 + 8 * (size_t)N_ROWS);

    k_zero<<<1, 256, 0, stream>>>((int*)ws);
    k_wnorm<<<K_CODES, 64, 0, stream>>>(w, wnorm2, wnormf);
    k_wfrag<<<48, 256, 0, stream>>>(w, wfrag);
    k_count<<<N_ROWS / 1024, 1024, 0, stream>>>(x, counts);
    k_scan<<<1, 64, 0, stream>>>(counts, bases, cursors);
    k_scatter<<<N_ROWS / 1024, 1024, 0, stream>>>(x, cursors, rowlist);
    k_passA<<<N_ROWS / BM + 5, 256, 0, stream>>>(e, w, counts, bases, rowlist, wfrag,
                                                 wnormf, out, loss, flagcnt, flagrows);
    k_passB<<<512, 256, 0, stream>>>(e, w, x, wnorm2, flagcnt, flagrows, out, loss);
    k_final<<<1, 64, 0, stream>>>(loss, out);
}